// Round 15
// baseline (66.747 us; speedup 1.0000x reference)
//
#include <hip/hip_runtime.h>
#include <hip/hip_bf16.h>

#define N_NODES 4096
#define F_IN 512
#define FHD 64
#define H_HEADS 8
#define C_OUT 512   /* H*FH */
#define ALPHA 0.2f
#define MAXE 192
#define MAXE_P 200
#define GEMM_BLOCKS 512

typedef __attribute__((ext_vector_type(8))) short bf16x8;
typedef __attribute__((ext_vector_type(4))) float f32x4;

static __device__ __forceinline__ unsigned short f2bf(float f) {
  __hip_bfloat16 h = __float2bfloat16(f);
  union { __hip_bfloat16 h; unsigned short u; } cvt;
  cvt.h = h;
  return cvt.u;
}

// ---------------------------------------------------------------------------
// conv: blocks [0,64) W transpose->bf16 | 64: zero colsum.
// ---------------------------------------------------------------------------
__global__ __launch_bounds__(256) void conv_kernel(
    const float* __restrict__ W, unsigned short* __restrict__ WbT,
    float* __restrict__ colsum) {
  __shared__ float sT[64][65];
  const int bid = blockIdx.x;
  const int tid = threadIdx.x;
  if (bid < 64) {
    const int fblk = bid & 7, h = bid >> 3;
#pragma unroll
    for (int i = 0; i < 16; ++i) {
      int idx = tid + i * 256;
      int f = idx >> 6, o = idx & 63;
      sT[f][o] = W[((size_t)h * F_IN + fblk * 64 + f) * FHD + o];
    }
    __syncthreads();
#pragma unroll
    for (int i = 0; i < 16; ++i) {
      int idx = tid + i * 256;
      int o = idx >> 6, f = idx & 63;
      WbT[(size_t)h * FHD * F_IN + (size_t)o * F_IN + fblk * 64 + f] =
          f2bf(sT[f][o]);
    }
  } else {
    colsum[tid] = 0.f;
    colsum[tid + 256] = 0.f;
  }
}

// ---------------------------------------------------------------------------
// gemm_scan v2: BK=32 -> LDS 21.5KB -> 7 blocks/CU (scan occupancy ~2x R14).
// blocks [0,512): MFMA GEMM 64 rows x 1 head; X cvt f32->bf16 in staging.
// blocks [512,4608): A-row CSR scan with NONTEMPORAL loads (keep L2 clean).
// ---------------------------------------------------------------------------
__global__ __launch_bounds__(256) void gemm_scan_kernel(
    const float* __restrict__ X, const unsigned short* __restrict__ WbT,
    const float* __restrict__ a_self, const float* __restrict__ a_neigh,
    const float* __restrict__ A,
    unsigned short* __restrict__ featsb,
    float* __restrict__ s_self, float* __restrict__ s_neigh,
    float* __restrict__ colsum,
    unsigned short* __restrict__ edges, int* __restrict__ degs) {
  __shared__ unsigned short sX[2][64 * 40];  // 64 rows x 32k, pad->40
  __shared__ unsigned short sW[2][64 * 40];
  __shared__ float sred[4][64];
  const int bid = blockIdx.x;
  const int tid = threadIdx.x;
  const int wid = tid >> 6, lane = tid & 63;

  if (bid >= GEMM_BLOCKS) {
    // ---- scan path
    const int i = bid - GEMM_BLOCKS;
    int* wave_tot = reinterpret_cast<int*>(&sred[0][0]);
    const f32x4* __restrict__ Arow4 =
        reinterpret_cast<const f32x4*>(A + (size_t)i * N_NODES);
    f32x4 v[4];
#pragma unroll
    for (int q = 0; q < 4; ++q)
      v[q] = __builtin_nontemporal_load(&Arow4[tid * 4 + q]);
    int mask16 = 0;
#pragma unroll
    for (int q = 0; q < 4; ++q) {
      mask16 |= (v[q].x != 0.f) ? (1 << (q * 4 + 0)) : 0;
      mask16 |= (v[q].y != 0.f) ? (1 << (q * 4 + 1)) : 0;
      mask16 |= (v[q].z != 0.f) ? (1 << (q * 4 + 2)) : 0;
      mask16 |= (v[q].w != 0.f) ? (1 << (q * 4 + 3)) : 0;
    }
    int cnt = __popc(mask16);
    int inc = cnt;
#pragma unroll
    for (int s = 1; s < 64; s <<= 1) {
      int t = __shfl_up(inc, s, 64);
      if (lane >= s) inc += t;
    }
    if (lane == 63) wave_tot[wid] = inc;
    __syncthreads();
    int wprefix = 0, tot = 0;
#pragma unroll
    for (int w = 0; w < 4; ++w) {
      int t = wave_tot[w];
      if (w < wid) wprefix += t;
      tot += t;
    }
    int pos = wprefix + inc - cnt;
    const int jbase = tid * 16;
    unsigned short* __restrict__ erow = edges + (size_t)i * MAXE;
    while (mask16) {
      int k = __ffs(mask16) - 1;
      mask16 &= mask16 - 1;
      if (pos < MAXE) erow[pos] = (unsigned short)(jbase + k);
      ++pos;
    }
    if (tid == 0) degs[i] = tot < MAXE ? tot : MAXE;
    return;
  }

  // ---- GEMM path (BK=32, 16 K-steps)
  const int h = bid >> 6;
  const int n0 = (bid & 63) * 64;
  const int l15 = lane & 15, l4 = lane >> 4;

  const int row = tid >> 2, seg = (tid & 3) * 8;  // 8 elems (16B bf16)/thread
  const float* xsrc = X + (size_t)(n0 + row) * F_IN + seg;
  const unsigned short* wsrc = WbT + ((size_t)h * FHD + row) * F_IN + seg;
  const int soff = row * 40 + seg;

  f32x4 acc[4];
#pragma unroll
  for (int j = 0; j < 4; ++j) acc[j] = (f32x4){0.f, 0.f, 0.f, 0.f};

  {
    float4 xa = *(const float4*)(xsrc);
    float4 xb = *(const float4*)(xsrc + 4);
    bf16x8 p;
    p[0] = f2bf(xa.x); p[1] = f2bf(xa.y); p[2] = f2bf(xa.z); p[3] = f2bf(xa.w);
    p[4] = f2bf(xb.x); p[5] = f2bf(xb.y); p[6] = f2bf(xb.z); p[7] = f2bf(xb.w);
    *(bf16x8*)&sX[0][soff] = p;
    *(bf16x8*)&sW[0][soff] = *(const bf16x8*)(wsrc);
  }
  __syncthreads();

  int cur = 0;
  for (int s = 0; s < 16; ++s) {
    float4 xa, xb;
    bf16x8 pw;
    const bool pf = (s < 15);
    if (pf) {
      const int k = (s + 1) * 32;
      xa = *(const float4*)(xsrc + k);
      xb = *(const float4*)(xsrc + k + 4);
      pw = *(const bf16x8*)(wsrc + k);
    }
    bf16x8 a = *(const bf16x8*)&sX[cur][(wid * 16 + l15) * 40 + l4 * 8];
#pragma unroll
    for (int tn = 0; tn < 4; ++tn) {
      bf16x8 b = *(const bf16x8*)&sW[cur][(tn * 16 + l15) * 40 + l4 * 8];
      acc[tn] =
          __builtin_amdgcn_mfma_f32_16x16x32_bf16(a, b, acc[tn], 0, 0, 0);
    }
    if (pf) {
      bf16x8 p;
      p[0] = f2bf(xa.x); p[1] = f2bf(xa.y); p[2] = f2bf(xa.z); p[3] = f2bf(xa.w);
      p[4] = f2bf(xb.x); p[5] = f2bf(xb.y); p[6] = f2bf(xb.z); p[7] = f2bf(xb.w);
      *(bf16x8*)&sX[cur ^ 1][soff] = p;
      *(bf16x8*)&sW[cur ^ 1][soff] = pw;
      __syncthreads();
      cur ^= 1;
    }
  }

  float aS[4], aN[4];
#pragma unroll
  for (int tn = 0; tn < 4; ++tn) {
    aS[tn] = a_self[h * FHD + tn * 16 + l15];
    aN[tn] = a_neigh[h * FHD + tn * 16 + l15];
  }
#pragma unroll
  for (int r = 0; r < 4; ++r) {
    const int grow = n0 + wid * 16 + l4 * 4 + r;
#pragma unroll
    for (int tn = 0; tn < 4; ++tn)
      featsb[(size_t)grow * C_OUT + h * FHD + tn * 16 + l15] =
          f2bf(acc[tn][r]);
    float ps = 0.f, pn = 0.f;
#pragma unroll
    for (int tn = 0; tn < 4; ++tn) {
      float v = acc[tn][r];
      ps = fmaf(v, aS[tn], ps);
      pn = fmaf(v, aN[tn], pn);
    }
#pragma unroll
    for (int sh = 1; sh < 16; sh <<= 1) {
      ps += __shfl_xor(ps, sh, 64);
      pn += __shfl_xor(pn, sh, 64);
    }
    if (l15 == 0) {
      s_self[grow * 8 + h] = ps;
      s_neigh[grow * 8 + h] = pn;
    }
  }

  float psum[4];
#pragma unroll
  for (int tn = 0; tn < 4; ++tn) {
    float s = acc[tn][0] + acc[tn][1] + acc[tn][2] + acc[tn][3];
    s += __shfl_xor(s, 16, 64);
    s += __shfl_xor(s, 32, 64);
    psum[tn] = s;
  }
  __syncthreads();
  if (l4 == 0) {
#pragma unroll
    for (int tn = 0; tn < 4; ++tn) sred[wid][tn * 16 + l15] = psum[tn];
  }
  __syncthreads();
  if (tid < 64) {
    float s = sred[0][tid] + sred[1][tid] + sred[2][tid] + sred[3][tid];
    atomicAdd(&colsum[h * FHD + tid], s);
  }
}

// ---------------------------------------------------------------------------
// attn v7: 8192 blocks = (row i) x (column half). bid%8 = XCD (HW
// round-robin): halves 0/1 pinned to XCDs 0-3/4-7 -> per-XCD gather working
// set = 2MB (fits 4MB L2, no thrash). Block computes only its 4 heads.
// Gather: lane owns 4 cols (8B/edge); wave = edge quarter; unroll-4.
// ---------------------------------------------------------------------------
__global__ __launch_bounds__(256) void attn_kernel(
    const unsigned short* __restrict__ edges, const int* __restrict__ degs,
    const unsigned short* __restrict__ featsb,
    const float* __restrict__ s_self, const float* __restrict__ s_neigh,
    const float* __restrict__ colsum, const float* __restrict__ bias,
    float* __restrict__ out) {
  const int bid = blockIdx.x;
  const int half = (bid & 7) >> 2;           // XCD group 0-3 / 4-7
  const int i = (bid >> 3) * 4 + (bid & 3);  // each (i,half) exactly once
  const int tid = threadIdx.x;
  const int wid = tid >> 6, lane = tid & 63;
  __shared__ int s_idx[MAXE];
  __shared__ int s_off[MAXE];          // j*1024 byte offsets
  __shared__ float s_w[4][MAXE_P];     // this block's 4 heads
  __shared__ float sh_self[4];
  __shared__ float sh_e0[4], sh_invZ[4];
  __shared__ float s_part[3][64][5];   // pad 5: conflict-free

  const int deg = degs[i];
  if (tid < 4) sh_self[tid] = s_self[i * 8 + half * 4 + tid];
  if (tid < deg) {
    int j = edges[(size_t)i * MAXE + tid];
    s_idx[tid] = j;
    s_off[tid] = j << 10;
  }
  __syncthreads();

  // Phase 1: logits for the 4 local heads
  for (int k = tid; k < deg * 4; k += 256) {
    int e = k >> 2, h4 = k & 3;
    int j = s_idx[e];
    float l = sh_self[h4] + s_neigh[j * 8 + half * 4 + h4];
    s_w[h4][e] = l > 0.f ? l : ALPHA * l;
  }
  __syncthreads();

  // Phase 2: softmax stats; wave wid owns local head wid
  {
    const int h4 = wid;
    float m = -1e30f;
    for (int e = lane; e < deg; e += 64) m = fmaxf(m, s_w[h4][e]);
#pragma unroll
    for (int s = 32; s > 0; s >>= 1) m = fmaxf(m, __shfl_xor(m, s, 64));
    m = fmaxf(m, 0.0f);  // non-edge dense entries are exactly 0
    float e0 = __expf(-m);
    float zs = 0.f;
    for (int e = lane; e < deg; e += 64) {
      float w = __expf(s_w[h4][e] - m);
      s_w[h4][e] = w - e0;  // minus colsum-correction share
      zs += w;
    }
#pragma unroll
    for (int s = 32; s > 0; s >>= 1) zs += __shfl_xor(zs, s, 64);
    if (lane == 0) {
      sh_e0[h4] = e0;
      sh_invZ[h4] = 1.0f / (zs + (float)(N_NODES - deg) * e0);
    }
  }
  __syncthreads();

  // Phase 3: gather. Lane owns 4 cols (8B); wave wid = edge quarter.
  const int h4 = lane >> 4;            // local head of this lane's cols
  const int q = wid;
  const int dq = (deg + 3) >> 2;
  const int ebeg = q * dq;
  const int eend = (ebeg + dq) < deg ? (ebeg + dq) : deg;
  const char* __restrict__ fbase =
      reinterpret_cast<const char*>(featsb) + half * 512 + lane * 8;
  float a0 = 0.f, a1 = 0.f, a2 = 0.f, a3 = 0.f;
  float c0 = 0.f, c1 = 0.f, c2 = 0.f, c3 = 0.f;
  int e = ebeg;
  for (; e + 3 < eend; e += 4) {
    float w0 = s_w[h4][e], w1 = s_w[h4][e + 1];
    float w2 = s_w[h4][e + 2], w3 = s_w[h4][e + 3];
    int o0 = s_off[e], o1 = s_off[e + 1];
    int o2 = s_off[e + 2], o3 = s_off[e + 3];
    uint2 u0 = *reinterpret_cast<const uint2*>(fbase + o0);
    uint2 u1 = *reinterpret_cast<const uint2*>(fbase + o1);
    uint2 u2 = *reinterpret_cast<const uint2*>(fbase + o2);
    uint2 u3 = *reinterpret_cast<const uint2*>(fbase + o3);
    a0 = fmaf(w0, __uint_as_float(u0.x << 16), a0);
    a1 = fmaf(w0, __uint_as_float(u0.x & 0xFFFF0000u), a1);
    a2 = fmaf(w0, __uint_as_float(u0.y << 16), a2);
    a3 = fmaf(w0, __uint_as_float(u0.y & 0xFFFF0000u), a3);
    c0 = fmaf(w1, __uint_as_float(u1.x << 16), c0);
    c1 = fmaf(w1, __uint_as_float(u1.x & 0xFFFF0000u), c1);
    c2 = fmaf(w1, __uint_as_float(u1.y << 16), c2);
    c3 = fmaf(w1, __uint_as_float(u1.y & 0xFFFF0000u), c3);
    a0 = fmaf(w2, __uint_as_float(u2.x << 16), a0);
    a1 = fmaf(w2, __uint_as_float(u2.x & 0xFFFF0000u), a1);
    a2 = fmaf(w2, __uint_as_float(u2.y << 16), a2);
    a3 = fmaf(w2, __uint_as_float(u2.y & 0xFFFF0000u), a3);
    c0 = fmaf(w3, __uint_as_float(u3.x << 16), c0);
    c1 = fmaf(w3, __uint_as_float(u3.x & 0xFFFF0000u), c1);
    c2 = fmaf(w3, __uint_as_float(u3.y << 16), c2);
    c3 = fmaf(w3, __uint_as_float(u3.y & 0xFFFF0000u), c3);
  }
  for (; e < eend; ++e) {
    float w0 = s_w[h4][e];
    uint2 u0 = *reinterpret_cast<const uint2*>(fbase + s_off[e]);
    a0 = fmaf(w0, __uint_as_float(u0.x << 16), a0);
    a1 = fmaf(w0, __uint_as_float(u0.x & 0xFFFF0000u), a1);
    a2 = fmaf(w0, __uint_as_float(u0.y << 16), a2);
    a3 = fmaf(w0, __uint_as_float(u0.y & 0xFFFF0000u), a3);
  }
  a0 += c0; a1 += c1; a2 += c2; a3 += c3;

  if (q > 0) {
    float* p = &s_part[q - 1][lane][0];
    p[0] = a0; p[1] = a1; p[2] = a2; p[3] = a3;
  }
  __syncthreads();
  if (q == 0) {
#pragma unroll
    for (int pp = 0; pp < 3; ++pp) {
      const float* p = &s_part[pp][lane][0];
      a0 += p[0]; a1 += p[1]; a2 += p[2]; a3 += p[3];
    }
    const int gc = half * 256 + lane * 4;  // global col base
    const float e0 = sh_e0[h4], invZ = sh_invZ[h4];
    const float4 cs = *reinterpret_cast<const float4*>(&colsum[gc]);
    const float4 bb = *reinterpret_cast<const float4*>(&bias[gc]);
    f32x4 o;
    float v;
    v = (a0 + e0 * cs.x) * invZ + bb.x; o.x = v > 0.f ? v : 0.f;
    v = (a1 + e0 * cs.y) * invZ + bb.y; o.y = v > 0.f ? v : 0.f;
    v = (a2 + e0 * cs.z) * invZ + bb.z; o.z = v > 0.f ? v : 0.f;
    v = (a3 + e0 * cs.w) * invZ + bb.w; o.w = v > 0.f ? v : 0.f;
    f32x4* dst = reinterpret_cast<f32x4*>(&out[(size_t)i * C_OUT + gc]);
    __builtin_nontemporal_store(o, dst);
  }
}

extern "C" void kernel_launch(void* const* d_in, const int* in_sizes, int n_in,
                              void* d_out, int out_size, void* d_ws, size_t ws_size,
                              hipStream_t stream) {
  const float* X = (const float*)d_in[0];
  const float* A = (const float*)d_in[1];
  const float* W = (const float*)d_in[2];
  const float* a_self = (const float*)d_in[3];
  const float* a_neigh = (const float*)d_in[4];
  const float* b = (const float*)d_in[5];
  float* out = (float*)d_out;

  char* ws = (char*)d_ws;
  unsigned short* featsb = (unsigned short*)ws;               // 4 MB
  char* p = ws + (size_t)N_NODES * C_OUT * 2;
  float* s_self = (float*)p;  p += N_NODES * H_HEADS * 4;     // 128 KB
  float* s_neigh = (float*)p; p += N_NODES * H_HEADS * 4;     // 128 KB
  float* colsum = (float*)p;  p += C_OUT * 4;                 // 2 KB
  int* degs = (int*)p;        p += N_NODES * 4;               // 16 KB
  unsigned short* edges = (unsigned short*)p;
  p += (size_t)N_NODES * MAXE * 2;                            // 1.5 MB
  unsigned short* WbT = (unsigned short*)p;                   // 512 KB

  conv_kernel<<<65, 256, 0, stream>>>(W, WbT, colsum);
  gemm_scan_kernel<<<GEMM_BLOCKS + N_NODES, 256, 0, stream>>>(
      X, WbT, a_self, a_neigh, A, featsb, s_self, s_neigh, colsum, edges,
      degs);
  attn_kernel<<<N_NODES * 2, 256, 0, stream>>>(edges, degs, featsb, s_self,
                                               s_neigh, colsum, b, out);
}

// Round 16
// 55.067 us; speedup vs baseline: 1.2121x; 1.2121x over previous
//
#include <hip/hip_runtime.h>
#include <hip/hip_bf16.h>

#define N_NODES 4096
#define F_IN 512
#define FHD 64
#define H_HEADS 8
#define C_OUT 512   /* H*FH */
#define ALPHA 0.2f
#define MAXE 192
#define MAXE_P 200
#define GEMM_BLOCKS 512

typedef __attribute__((ext_vector_type(8))) short bf16x8;
typedef __attribute__((ext_vector_type(4))) float f32x4;

static __device__ __forceinline__ unsigned short f2bf(float f) {
  __hip_bfloat16 h = __float2bfloat16(f);
  union { __hip_bfloat16 h; unsigned short u; } cvt;
  cvt.h = h;
  return cvt.u;
}

// ---------------------------------------------------------------------------
// conv: blocks [0,64) W transpose->bf16 | 64: zero colsum.  (R14 verbatim)
// ---------------------------------------------------------------------------
__global__ __launch_bounds__(256) void conv_kernel(
    const float* __restrict__ W, unsigned short* __restrict__ WbT,
    float* __restrict__ colsum) {
  __shared__ float sT[64][65];
  const int bid = blockIdx.x;
  const int tid = threadIdx.x;
  if (bid < 64) {
    const int fblk = bid & 7, h = bid >> 3;
#pragma unroll
    for (int i = 0; i < 16; ++i) {
      int idx = tid + i * 256;
      int f = idx >> 6, o = idx & 63;
      sT[f][o] = W[((size_t)h * F_IN + fblk * 64 + f) * FHD + o];
    }
    __syncthreads();
#pragma unroll
    for (int i = 0; i < 16; ++i) {
      int idx = tid + i * 256;
      int o = idx >> 6, f = idx & 63;
      WbT[(size_t)h * FHD * F_IN + (size_t)o * F_IN + fblk * 64 + f] =
          f2bf(sT[f][o]);
    }
  } else {
    colsum[tid] = 0.f;
    colsum[tid + 256] = 0.f;
  }
}

// ---------------------------------------------------------------------------
// gemm_scan (R14 verbatim): blocks [0,512) MFMA GEMM (BK=64, dbuf, in-staging
// f32->bf16 cvt); blocks [512,4608) A-row CSR scan. Co-resident overlap.
// ---------------------------------------------------------------------------
__global__ __launch_bounds__(256) void gemm_scan_kernel(
    const float* __restrict__ X, const unsigned short* __restrict__ WbT,
    const float* __restrict__ a_self, const float* __restrict__ a_neigh,
    const float* __restrict__ A,
    unsigned short* __restrict__ featsb,
    float* __restrict__ s_self, float* __restrict__ s_neigh,
    float* __restrict__ colsum,
    unsigned short* __restrict__ edges, int* __restrict__ degs) {
  __shared__ unsigned short sX[2][64 * 72];
  __shared__ unsigned short sW[2][64 * 72];
  __shared__ float sred[4][64];
  const int bid = blockIdx.x;
  const int tid = threadIdx.x;
  const int wid = tid >> 6, lane = tid & 63;

  if (bid >= GEMM_BLOCKS) {
    // ---- scan path: CSR build for row i
    const int i = bid - GEMM_BLOCKS;
    int* wave_tot = reinterpret_cast<int*>(&sred[0][0]);
    const float4* __restrict__ Arow4 =
        reinterpret_cast<const float4*>(A + (size_t)i * N_NODES);
    float4 v[4];
#pragma unroll
    for (int q = 0; q < 4; ++q) v[q] = Arow4[tid * 4 + q];
    int mask16 = 0;
#pragma unroll
    for (int q = 0; q < 4; ++q) {
      mask16 |= (v[q].x != 0.f) ? (1 << (q * 4 + 0)) : 0;
      mask16 |= (v[q].y != 0.f) ? (1 << (q * 4 + 1)) : 0;
      mask16 |= (v[q].z != 0.f) ? (1 << (q * 4 + 2)) : 0;
      mask16 |= (v[q].w != 0.f) ? (1 << (q * 4 + 3)) : 0;
    }
    int cnt = __popc(mask16);
    int inc = cnt;
#pragma unroll
    for (int s = 1; s < 64; s <<= 1) {
      int t = __shfl_up(inc, s, 64);
      if (lane >= s) inc += t;
    }
    if (lane == 63) wave_tot[wid] = inc;
    __syncthreads();
    int wprefix = 0, tot = 0;
#pragma unroll
    for (int w = 0; w < 4; ++w) {
      int t = wave_tot[w];
      if (w < wid) wprefix += t;
      tot += t;
    }
    int pos = wprefix + inc - cnt;
    const int jbase = tid * 16;
    unsigned short* __restrict__ erow = edges + (size_t)i * MAXE;
    while (mask16) {
      int k = __ffs(mask16) - 1;
      mask16 &= mask16 - 1;
      if (pos < MAXE) erow[pos] = (unsigned short)(jbase + k);
      ++pos;
    }
    if (tid == 0) degs[i] = tot < MAXE ? tot : MAXE;
    return;
  }

  // ---- GEMM path
  const int h = bid >> 6;
  const int n0 = (bid & 63) * 64;
  const int l15 = lane & 15, l4 = lane >> 4;

  const int row = tid >> 2, seg = (tid & 3) * 16;
  const float* xsrc = X + (size_t)(n0 + row) * F_IN + seg;
  const unsigned short* wsrc = WbT + ((size_t)h * FHD + row) * F_IN + seg;
  const int soff = row * 72 + seg;

  f32x4 acc[4];
#pragma unroll
  for (int j = 0; j < 4; ++j) acc[j] = (f32x4){0.f, 0.f, 0.f, 0.f};

  {
    float4 xa = *(const float4*)(xsrc);
    float4 xb = *(const float4*)(xsrc + 4);
    float4 xc = *(const float4*)(xsrc + 8);
    float4 xd = *(const float4*)(xsrc + 12);
    bf16x8 p0, p1;
    p0[0] = f2bf(xa.x); p0[1] = f2bf(xa.y); p0[2] = f2bf(xa.z); p0[3] = f2bf(xa.w);
    p0[4] = f2bf(xb.x); p0[5] = f2bf(xb.y); p0[6] = f2bf(xb.z); p0[7] = f2bf(xb.w);
    p1[0] = f2bf(xc.x); p1[1] = f2bf(xc.y); p1[2] = f2bf(xc.z); p1[3] = f2bf(xc.w);
    p1[4] = f2bf(xd.x); p1[5] = f2bf(xd.y); p1[6] = f2bf(xd.z); p1[7] = f2bf(xd.w);
    *(bf16x8*)&sX[0][soff] = p0;
    *(bf16x8*)&sX[0][soff + 8] = p1;
    *(bf16x8*)&sW[0][soff] = *(const bf16x8*)(wsrc);
    *(bf16x8*)&sW[0][soff + 8] = *(const bf16x8*)(wsrc + 8);
  }
  __syncthreads();

  int cur = 0;
  for (int s = 0; s < 8; ++s) {
    float4 xa, xb, xc, xd;
    bf16x8 pw0, pw1;
    const bool pf = (s < 7);
    if (pf) {
      const int k = (s + 1) * 64;
      xa = *(const float4*)(xsrc + k);
      xb = *(const float4*)(xsrc + k + 4);
      xc = *(const float4*)(xsrc + k + 8);
      xd = *(const float4*)(xsrc + k + 12);
      pw0 = *(const bf16x8*)(wsrc + k);
      pw1 = *(const bf16x8*)(wsrc + k + 8);
    }
#pragma unroll
    for (int kk = 0; kk < 2; ++kk) {
      bf16x8 a = *(const bf16x8*)&sX[cur][(wid * 16 + l15) * 72 + kk * 32 + l4 * 8];
#pragma unroll
      for (int tn = 0; tn < 4; ++tn) {
        bf16x8 b = *(const bf16x8*)&sW[cur][(tn * 16 + l15) * 72 + kk * 32 + l4 * 8];
        acc[tn] =
            __builtin_amdgcn_mfma_f32_16x16x32_bf16(a, b, acc[tn], 0, 0, 0);
      }
    }
    if (pf) {
      bf16x8 p0, p1;
      p0[0] = f2bf(xa.x); p0[1] = f2bf(xa.y); p0[2] = f2bf(xa.z); p0[3] = f2bf(xa.w);
      p0[4] = f2bf(xb.x); p0[5] = f2bf(xb.y); p0[6] = f2bf(xb.z); p0[7] = f2bf(xb.w);
      p1[0] = f2bf(xc.x); p1[1] = f2bf(xc.y); p1[2] = f2bf(xc.z); p1[3] = f2bf(xc.w);
      p1[4] = f2bf(xd.x); p1[5] = f2bf(xd.y); p1[6] = f2bf(xd.z); p1[7] = f2bf(xd.w);
      *(bf16x8*)&sX[cur ^ 1][soff] = p0;
      *(bf16x8*)&sX[cur ^ 1][soff + 8] = p1;
      *(bf16x8*)&sW[cur ^ 1][soff] = pw0;
      *(bf16x8*)&sW[cur ^ 1][soff + 8] = pw1;
      __syncthreads();
      cur ^= 1;
    }
  }

  float aS[4], aN[4];
#pragma unroll
  for (int tn = 0; tn < 4; ++tn) {
    aS[tn] = a_self[h * FHD + tn * 16 + l15];
    aN[tn] = a_neigh[h * FHD + tn * 16 + l15];
  }
#pragma unroll
  for (int r = 0; r < 4; ++r) {
    const int grow = n0 + wid * 16 + l4 * 4 + r;
#pragma unroll
    for (int tn = 0; tn < 4; ++tn)
      featsb[(size_t)grow * C_OUT + h * FHD + tn * 16 + l15] =
          f2bf(acc[tn][r]);
    float ps = 0.f, pn = 0.f;
#pragma unroll
    for (int tn = 0; tn < 4; ++tn) {
      float v = acc[tn][r];
      ps = fmaf(v, aS[tn], ps);
      pn = fmaf(v, aN[tn], pn);
    }
#pragma unroll
    for (int sh = 1; sh < 16; sh <<= 1) {
      ps += __shfl_xor(ps, sh, 64);
      pn += __shfl_xor(pn, sh, 64);
    }
    if (l15 == 0) {
      s_self[grow * 8 + h] = ps;
      s_neigh[grow * 8 + h] = pn;
    }
  }

  float psum[4];
#pragma unroll
  for (int tn = 0; tn < 4; ++tn) {
    float s = acc[tn][0] + acc[tn][1] + acc[tn][2] + acc[tn][3];
    s += __shfl_xor(s, 16, 64);
    s += __shfl_xor(s, 32, 64);
    psum[tn] = s;
  }
  __syncthreads();
  if (l4 == 0) {
#pragma unroll
    for (int tn = 0; tn < 4; ++tn) sred[wid][tn * 16 + l15] = psum[tn];
  }
  __syncthreads();
  if (tid < 64) {
    float s = sred[0][tid] + sred[1][tid] + sred[2][tid] + sred[3][tid];
    atomicAdd(&colsum[h * FHD + tid], s);
  }
}

// ---------------------------------------------------------------------------
// attn v8: 8192 blocks = (row i) x (column half); bid%8 -> XCD (round-robin
// heuristic) pins half 0 to XCDs 0-3, half 1 to XCDs 4-7 -> per-XCD gather
// working set 2MB (fits 4MB L2). Unlike v7, keeps 16B/lane: each wave-iter
// covers 2 edges (lanes 0-31 edge e, lanes 32-63 edge e+1), 16B x 32 lanes
// = the 512B half-row each. Unroll-2 -> 4 edges / 2KB in flight per wave.
// ---------------------------------------------------------------------------
__global__ __launch_bounds__(256) void attn_kernel(
    const unsigned short* __restrict__ edges, const int* __restrict__ degs,
    const unsigned short* __restrict__ featsb,
    const float* __restrict__ s_self, const float* __restrict__ s_neigh,
    const float* __restrict__ colsum, const float* __restrict__ bias,
    float* __restrict__ out) {
  const int bid = blockIdx.x;
  const int half = (bid & 7) >> 2;           // XCD group 0-3 / 4-7
  const int i = (bid >> 3) * 4 + (bid & 3);  // each (i,half) exactly once
  const int tid = threadIdx.x;
  const int wid = tid >> 6, lane = tid & 63;
  __shared__ int s_idx[MAXE];
  __shared__ int s_off[MAXE];          // j*1024 byte offsets
  __shared__ float s_w[4][MAXE_P];     // this block's 4 heads
  __shared__ float sh_self[4];
  __shared__ float sh_e0[4], sh_invZ[4];
  __shared__ float s_part[7][32][9];   // 7 partial sets, conflict-free pad

  const int deg = degs[i];
  if (tid < 4) sh_self[tid] = s_self[i * 8 + half * 4 + tid];
  if (tid < deg) {
    int j = edges[(size_t)i * MAXE + tid];
    s_idx[tid] = j;
    s_off[tid] = j << 10;
  }
  __syncthreads();

  // Phase 1: logits for the 4 local heads
  for (int k = tid; k < deg * 4; k += 256) {
    int e = k >> 2, h4 = k & 3;
    int j = s_idx[e];
    float l = sh_self[h4] + s_neigh[j * 8 + half * 4 + h4];
    s_w[h4][e] = l > 0.f ? l : ALPHA * l;
  }
  __syncthreads();

  // Phase 2: softmax stats; wave wid owns local head wid
  {
    const int h4 = wid;
    float m = -1e30f;
    for (int e = lane; e < deg; e += 64) m = fmaxf(m, s_w[h4][e]);
#pragma unroll
    for (int s = 32; s > 0; s >>= 1) m = fmaxf(m, __shfl_xor(m, s, 64));
    m = fmaxf(m, 0.0f);  // non-edge dense entries are exactly 0
    float e0 = __expf(-m);
    float zs = 0.f;
    for (int e = lane; e < deg; e += 64) {
      float w = __expf(s_w[h4][e] - m);
      s_w[h4][e] = w - e0;  // minus colsum-correction share
      zs += w;
    }
#pragma unroll
    for (int s = 32; s > 0; s >>= 1) zs += __shfl_xor(zs, s, 64);
    if (lane == 0) {
      sh_e0[h4] = e0;
      sh_invZ[h4] = 1.0f / (zs + (float)(N_NODES - deg) * e0);
    }
  }
  __syncthreads();

  // Phase 3: gather. sub = which of 2 edges this lane covers; cl = 16B col
  // chunk within the half-row (32 chunks x 16B = 512B). Wave = edge quarter.
  const int sub = lane >> 5;           // 0/1
  const int cl = lane & 31;            // col chunk
  const int h4 = cl >> 3;              // local head of these 8 cols
  const int q = wid;
  const int dq = (deg + 3) >> 2;
  const int ebeg = q * dq;
  const int eend = (ebeg + dq) < deg ? (ebeg + dq) : deg;
  const char* __restrict__ fbase =
      reinterpret_cast<const char*>(featsb) + half * 512 + cl * 16;
  float a0 = 0.f, a1 = 0.f, a2 = 0.f, a3 = 0.f;
  float a4 = 0.f, a5 = 0.f, a6 = 0.f, a7 = 0.f;
  float c0 = 0.f, c1 = 0.f, c2 = 0.f, c3 = 0.f;
  float c4 = 0.f, c5 = 0.f, c6 = 0.f, c7 = 0.f;
  int e = ebeg;
  for (; e + 3 < eend; e += 4) {
    float w0 = s_w[h4][e + sub];
    float w1 = s_w[h4][e + 2 + sub];
    int o0 = s_off[e + sub], o1 = s_off[e + 2 + sub];
    uint4 u0 = *reinterpret_cast<const uint4*>(fbase + o0);
    uint4 u1 = *reinterpret_cast<const uint4*>(fbase + o1);
    a0 = fmaf(w0, __uint_as_float(u0.x << 16), a0);
    a1 = fmaf(w0, __uint_as_float(u0.x & 0xFFFF0000u), a1);
    a2 = fmaf(w0, __uint_as_float(u0.y << 16), a2);
    a3 = fmaf(w0, __uint_as_float(u0.y & 0xFFFF0000u), a3);
    a4 = fmaf(w0, __uint_as_float(u0.z << 16), a4);
    a5 = fmaf(w0, __uint_as_float(u0.z & 0xFFFF0000u), a5);
    a6 = fmaf(w0, __uint_as_float(u0.w << 16), a6);
    a7 = fmaf(w0, __uint_as_float(u0.w & 0xFFFF0000u), a7);
    c0 = fmaf(w1, __uint_as_float(u1.x << 16), c0);
    c1 = fmaf(w1, __uint_as_float(u1.x & 0xFFFF0000u), c1);
    c2 = fmaf(w1, __uint_as_float(u1.y << 16), c2);
    c3 = fmaf(w1, __uint_as_float(u1.y & 0xFFFF0000u), c3);
    c4 = fmaf(w1, __uint_as_float(u1.z << 16), c4);
    c5 = fmaf(w1, __uint_as_float(u1.z & 0xFFFF0000u), c5);
    c6 = fmaf(w1, __uint_as_float(u1.w << 16), c6);
    c7 = fmaf(w1, __uint_as_float(u1.w & 0xFFFF0000u), c7);
  }
  for (; e + sub < eend; e += 2) {  // per-lane tail (exec-mask divergence ok)
    float w0 = s_w[h4][e + sub];
    uint4 u0 = *reinterpret_cast<const uint4*>(fbase + s_off[e + sub]);
    a0 = fmaf(w0, __uint_as_float(u0.x << 16), a0);
    a1 = fmaf(w0, __uint_as_float(u0.x & 0xFFFF0000u), a1);
    a2 = fmaf(w0, __uint_as_float(u0.y << 16), a2);
    a3 = fmaf(w0, __uint_as_float(u0.y & 0xFFFF0000u), a3);
    a4 = fmaf(w0, __uint_as_float(u0.z << 16), a4);
    a5 = fmaf(w0, __uint_as_float(u0.z & 0xFFFF0000u), a5);
    a6 = fmaf(w0, __uint_as_float(u0.w << 16), a6);
    a7 = fmaf(w0, __uint_as_float(u0.w & 0xFFFF0000u), a7);
  }
  a0 += c0; a1 += c1; a2 += c2; a3 += c3;
  a4 += c4; a5 += c5; a6 += c6; a7 += c7;

  const int pidx = q * 2 + sub;        // 0..7; 0 is the combiner
  if (pidx > 0) {
    float* p = &s_part[pidx - 1][cl][0];
    p[0] = a0; p[1] = a1; p[2] = a2; p[3] = a3;
    p[4] = a4; p[5] = a5; p[6] = a6; p[7] = a7;
  }
  __syncthreads();
  if (pidx == 0) {
#pragma unroll
    for (int pp = 0; pp < 7; ++pp) {
      const float* p = &s_part[pp][cl][0];
      a0 += p[0]; a1 += p[1]; a2 += p[2]; a3 += p[3];
      a4 += p[4]; a5 += p[5]; a6 += p[6]; a7 += p[7];
    }
    const int gc = half * 256 + cl * 8;  // global col base
    const float e0 = sh_e0[h4], invZ = sh_invZ[h4];
    const float4 cs0 = *reinterpret_cast<const float4*>(&colsum[gc]);
    const float4 cs1 = *reinterpret_cast<const float4*>(&colsum[gc + 4]);
    const float4 bb0 = *reinterpret_cast<const float4*>(&bias[gc]);
    const float4 bb1 = *reinterpret_cast<const float4*>(&bias[gc + 4]);
    f32x4 o0, o1;
    float v;
    v = (a0 + e0 * cs0.x) * invZ + bb0.x; o0.x = v > 0.f ? v : 0.f;
    v = (a1 + e0 * cs0.y) * invZ + bb0.y; o0.y = v > 0.f ? v : 0.f;
    v = (a2 + e0 * cs0.z) * invZ + bb0.z; o0.z = v > 0.f ? v : 0.f;
    v = (a3 + e0 * cs0.w) * invZ + bb0.w; o0.w = v > 0.f ? v : 0.f;
    v = (a4 + e0 * cs1.x) * invZ + bb1.x; o1.x = v > 0.f ? v : 0.f;
    v = (a5 + e0 * cs1.y) * invZ + bb1.y; o1.y = v > 0.f ? v : 0.f;
    v = (a6 + e0 * cs1.z) * invZ + bb1.z; o1.z = v > 0.f ? v : 0.f;
    v = (a7 + e0 * cs1.w) * invZ + bb1.w; o1.w = v > 0.f ? v : 0.f;
    f32x4* dst = reinterpret_cast<f32x4*>(&out[(size_t)i * C_OUT + gc]);
    __builtin_nontemporal_store(o0, dst);
    __builtin_nontemporal_store(o1, dst + 1);
  }
}

extern "C" void kernel_launch(void* const* d_in, const int* in_sizes, int n_in,
                              void* d_out, int out_size, void* d_ws, size_t ws_size,
                              hipStream_t stream) {
  const float* X = (const float*)d_in[0];
  const float* A = (const float*)d_in[1];
  const float* W = (const float*)d_in[2];
  const float* a_self = (const float*)d_in[3];
  const float* a_neigh = (const float*)d_in[4];
  const float* b = (const float*)d_in[5];
  float* out = (float*)d_out;

  char* ws = (char*)d_ws;
  unsigned short* featsb = (unsigned short*)ws;               // 4 MB
  char* p = ws + (size_t)N_NODES * C_OUT * 2;
  float* s_self = (float*)p;  p += N_NODES * H_HEADS * 4;     // 128 KB
  float* s_neigh = (float*)p; p += N_NODES * H_HEADS * 4;     // 128 KB
  float* colsum = (float*)p;  p += C_OUT * 4;                 // 2 KB
  int* degs = (int*)p;        p += N_NODES * 4;               // 16 KB
  unsigned short* edges = (unsigned short*)p;
  p += (size_t)N_NODES * MAXE * 2;                            // 1.5 MB
  unsigned short* WbT = (unsigned short*)p;                   // 512 KB

  conv_kernel<<<65, 256, 0, stream>>>(W, WbT, colsum);
  gemm_scan_kernel<<<GEMM_BLOCKS + N_NODES, 256, 0, stream>>>(
      X, WbT, a_self, a_neigh, A, featsb, s_self, s_neigh, colsum, edges,
      degs);
  attn_kernel<<<N_NODES * 2, 256, 0, stream>>>(edges, degs, featsb, s_self,
                                               s_neigh, colsum, b, out);
}